// Round 2
// baseline (4202.823 us; speedup 1.0000x reference)
//
#include <hip/hip_runtime.h>
#include <math.h>

#define DD 256
#define NH 8

typedef __attribute__((ext_vector_type(8))) short short8;
typedef __attribute__((ext_vector_type(4))) float floatx4;

__device__ __forceinline__ float b2f(unsigned short u) {
    return __uint_as_float(((unsigned)u) << 16);
}
__device__ __forceinline__ unsigned short f2b(float f) {
    unsigned u = __float_as_uint(f);
    return (unsigned short)((u + 0x7fffu + ((u >> 16) & 1u)) >> 16);
}
// monotonic float->uint encoding for atomicMax over signed floats
__device__ __forceinline__ unsigned encf(float x) {
    unsigned u = __float_as_uint(x);
    return (u & 0x80000000u) ? ~u : (u | 0x80000000u);
}
__device__ __forceinline__ float decf(unsigned e) {
    unsigned u = (e & 0x80000000u) ? (e ^ 0x80000000u) : ~e;
    return __uint_as_float(u);
}

// ln_att_v_g is all-ones: f32 word0 = 0x3F800000, bf16 word0 = 0x3F803F80
__global__ void detect_dtype(const unsigned* __restrict__ ones_words, int* __restrict__ flag) {
    flag[0] = (ones_words[0] == 0x3F800000u) ? 0 : 1;   // 0 = f32 external, 1 = bf16 external
}

// load 8 consecutive elements as bf16 (f32 path converts on the fly)
__device__ __forceinline__ void load8(const void* base, size_t off, int f32, unsigned short* dst) {
    if (f32) {
        const float4* p = (const float4*)((const float*)base + off);
        float4 x = p[0], y = p[1];
        dst[0] = f2b(x.x); dst[1] = f2b(x.y); dst[2] = f2b(x.z); dst[3] = f2b(x.w);
        dst[4] = f2b(y.x); dst[5] = f2b(y.y); dst[6] = f2b(y.z); dst[7] = f2b(y.w);
    } else {
        *(uint4*)dst = *(const uint4*)((const unsigned short*)base + off);
    }
}

// C = A(MxK=256) @ W(256xN) + bias. A external iff A_EXT (else internal bf16).
// W/bias always external. EPI: 0=bf16 store, 1=gelu->bf16, 2=f32 store
template<int A_EXT, int EPI>
__launch_bounds__(256)
__global__ void gemm_k256(const void* __restrict__ A, int M,
                          const void* __restrict__ W, int ldw,
                          const void* __restrict__ bias,
                          void* __restrict__ outp, const int* __restrict__ flagp)
{
    const int extf = (*flagp == 0);   // 1 if external tensors are f32
    __shared__ __align__(16) short As[64][32];
    __shared__ __align__(16) short Bs[64][32];   // B transposed: Bs[n][k]
    const int t = threadIdx.x;
    const int wave = t >> 6, lane = t & 63;
    const int m0 = blockIdx.x * 64, n0 = blockIdx.y * 64;
    floatx4 acc[4] = {};
    const int arow = t >> 2, acol = (t & 3) * 8;  // A: 64 rows x 32 k
    const int wrow = t >> 3, wcol = (t & 7) * 8;  // W: 32 rows x 64 n
    const int fr = lane & 15, fq = lane >> 4;

    for (int k0 = 0; k0 < DD; k0 += 32) {
        unsigned short a8[8] = {0, 0, 0, 0, 0, 0, 0, 0};
        if (m0 + arow < M)
            load8(A, (size_t)(m0 + arow) * DD + k0 + acol, A_EXT && extf, a8);
        *(uint4*)(&As[arow][acol]) = *(const uint4*)a8;
        unsigned short w8[8];
        load8(W, (size_t)(k0 + wrow) * ldw + n0 + wcol, extf, w8);
        #pragma unroll
        for (int j = 0; j < 8; ++j) Bs[wcol + j][wrow] = (short)w8[j];
        __syncthreads();
        // A frag: A[m=lane&15][k=(lane>>4)*8+j]; B frag: B[n=lane&15][k=(lane>>4)*8+j]
        short8 af = *(const short8*)(&As[wave * 16 + fr][fq * 8]);
        #pragma unroll
        for (int j = 0; j < 4; ++j) {
            short8 bf = *(const short8*)(&Bs[j * 16 + fr][fq * 8]);
            acc[j] = __builtin_amdgcn_mfma_f32_16x16x32_bf16(af, bf, acc[j], 0, 0, 0);
        }
        __syncthreads();
    }
    #pragma unroll
    for (int j = 0; j < 4; ++j) {
        int col = n0 + j * 16 + fr;
        float bv = extf ? ((const float*)bias)[col] : b2f(((const unsigned short*)bias)[col]);
        #pragma unroll
        for (int r = 0; r < 4; ++r) {
            int row = m0 + wave * 16 + fq * 4 + r;
            if (row < M) {
                float x = acc[j][r] + bv;
                if (EPI == 1) x = 0.5f * x * (1.0f + erff(x * 0.70710678118654752f));
                if (EPI == 2) {
                    ((float*)outp)[(size_t)row * ldw + col] = x;
                } else {
                    ((unsigned short*)outp)[(size_t)row * ldw + col] = f2b(x);
                }
            }
        }
    }
}

// thread per (edge, dir, head): 32-dot, store logit, atomicMax per (seg,head)
__launch_bounds__(256)
__global__ void edge_logits(const int* __restrict__ adj, int E, int NV,
                            const unsigned short* __restrict__ qbuf,
                            const unsigned short* __restrict__ kvbuf,
                            float* __restrict__ qk, unsigned* __restrict__ mbuf)
{
    int t = blockIdx.x * 256 + threadIdx.x;
    if (t >= E * 16) return;
    int e = t >> 4, rem = t & 15;
    int dir = rem >> 3, h = rem & 7;
    int ce = adj[e], xe = adj[E + e];
    int qrow = dir ? (NV + ce) : xe;
    int krow = dir ? xe : (NV + ce);
    const unsigned short* qp = qbuf + (size_t)qrow * DD + h * 32;
    const unsigned short* kp = kvbuf + (size_t)krow * 512 + h * 32;
    float s = 0.f;
    #pragma unroll
    for (int i = 0; i < 4; ++i) {
        uint4 qv = ((const uint4*)qp)[i];
        uint4 kv = ((const uint4*)kp)[i];
        const unsigned short* qa = (const unsigned short*)&qv;
        const unsigned short* ka = (const unsigned short*)&kv;
        #pragma unroll
        for (int j = 0; j < 8; ++j) s += b2f(qa[j]) * b2f(ka[j]);
    }
    s *= 0.17677669529663689f;   // 1/sqrt(32)
    qk[t] = s;
    atomicMax(mbuf + (size_t)qrow * NH + h, encf(s));
}

__launch_bounds__(256)
__global__ void edge_exp(const int* __restrict__ adj, int E, int NV,
                         float* __restrict__ qk, const unsigned* __restrict__ mbuf,
                         float* __restrict__ sbuf)
{
    int t = blockIdx.x * 256 + threadIdx.x;
    if (t >= E * 16) return;
    int e = t >> 4, rem = t & 15;
    int dir = rem >> 3, h = rem & 7;
    int ce = adj[e], xe = adj[E + e];
    int seg = dir ? (NV + ce) : xe;
    float m = decf(mbuf[(size_t)seg * NH + h]);
    float ex = expf(qk[t] - m);
    qk[t] = ex;
    unsafeAtomicAdd(sbuf + (size_t)seg * NH + h, ex);
}

// thread per (edge, dir, 8-channel group): alpha * V scatter
__launch_bounds__(256)
__global__ void edge_agg(const int* __restrict__ adj, int E, int NV,
                         const float* __restrict__ qk, const float* __restrict__ sbuf,
                         const unsigned short* __restrict__ kvbuf,
                         float* __restrict__ osum)
{
    int t = blockIdx.x * 256 + threadIdx.x;
    if (t >= E * 64) return;
    int idx = t >> 5, g = t & 31;       // idx = e*2+dir
    int e = idx >> 1, dir = idx & 1;
    int ce = adj[e], xe = adj[E + e];
    int seg = dir ? (NV + ce) : xe;
    int krow = dir ? xe : (NV + ce);
    int ch = g * 8, h = g >> 2;
    float alpha = qk[idx * 8 + h] / sbuf[(size_t)seg * NH + h];
    const unsigned short* vp = kvbuf + (size_t)krow * 512 + DD + ch;
    uint4 vv = *(const uint4*)vp;
    const unsigned short* va = (const unsigned short*)&vv;
    float* op = osum + (size_t)seg * DD + ch;
    #pragma unroll
    for (int i = 0; i < 8; ++i) unsafeAtomicAdd(op + i, alpha * b2f(va[i]));
}

// LN(base + add). BASE_EXT: base is external tensor; OUT_EXT: out is d_out.
template<int BASE_EXT, int OUT_EXT>
__launch_bounds__(256)
__global__ void ln_res(const void* __restrict__ baseA, const void* __restrict__ baseB,
                       const float* __restrict__ add,
                       const void* __restrict__ gA, const void* __restrict__ bA,
                       const void* __restrict__ gB, const void* __restrict__ bB,
                       void* __restrict__ out, int NA, int Ntot, const int* __restrict__ flagp)
{
    int row = blockIdx.x * 4 + (threadIdx.x >> 6);
    if (row >= Ntot) return;
    int lane = threadIdx.x & 63;
    const int extf = (*flagp == 0);
    const void *base, *g, *b;
    size_t roff;
    if (row < NA) { base = baseA; g = gA; b = bA; roff = (size_t)row * DD; }
    else          { base = baseB; g = gB; b = bB; roff = (size_t)(row - NA) * DD; }
    float4 a = ((const float4*)(add + (size_t)row * DD))[lane];
    float y0, y1, y2, y3;
    if (BASE_EXT && extf) {
        float4 t = ((const float4*)((const float*)base + roff))[lane];
        y0 = t.x; y1 = t.y; y2 = t.z; y3 = t.w;
    } else {
        ushort4 t = ((const ushort4*)((const unsigned short*)base + roff))[lane];
        y0 = b2f(t.x); y1 = b2f(t.y); y2 = b2f(t.z); y3 = b2f(t.w);
    }
    y0 += a.x; y1 += a.y; y2 += a.z; y3 += a.w;
    float s = y0 + y1 + y2 + y3;
    #pragma unroll
    for (int off = 32; off; off >>= 1) s += __shfl_xor(s, off);
    float mean = s * (1.0f / DD);
    float d0 = y0 - mean, d1 = y1 - mean, d2 = y2 - mean, d3 = y3 - mean;
    float v = d0 * d0 + d1 * d1 + d2 * d2 + d3 * d3;
    #pragma unroll
    for (int off = 32; off; off >>= 1) v += __shfl_xor(v, off);
    float rstd = rsqrtf(v * (1.0f / DD) + 1e-5f);
    float g0, g1, g2, g3, t0, t1, t2, t3;
    if (extf) {
        float4 gg = ((const float4*)g)[lane]; float4 bt = ((const float4*)b)[lane];
        g0 = gg.x; g1 = gg.y; g2 = gg.z; g3 = gg.w;
        t0 = bt.x; t1 = bt.y; t2 = bt.z; t3 = bt.w;
    } else {
        ushort4 gg = ((const ushort4*)g)[lane]; ushort4 bt = ((const ushort4*)b)[lane];
        g0 = b2f(gg.x); g1 = b2f(gg.y); g2 = b2f(gg.z); g3 = b2f(gg.w);
        t0 = b2f(bt.x); t1 = b2f(bt.y); t2 = b2f(bt.z); t3 = b2f(bt.w);
    }
    float o0 = d0 * rstd * g0 + t0, o1 = d1 * rstd * g1 + t1;
    float o2 = d2 * rstd * g2 + t2, o3 = d3 * rstd * g3 + t3;
    if (OUT_EXT && extf) {
        float4 o; o.x = o0; o.y = o1; o.z = o2; o.w = o3;
        ((float4*)((float*)out + (size_t)row * DD))[lane] = o;
    } else {
        ushort4 o;
        o.x = f2b(o0); o.y = f2b(o1); o.z = f2b(o2); o.w = f2b(o3);
        ((ushort4*)((unsigned short*)out + (size_t)row * DD))[lane] = o;
    }
}

extern "C" void kernel_launch(void* const* d_in, const int* in_sizes, int n_in,
                              void* d_out, int out_size, void* d_ws, size_t ws_size,
                              hipStream_t stream)
{
    const void* v   = d_in[0];
    const void* c   = d_in[1];
    const int* adj_pos = (const int*)d_in[2];
    const int* adj_neg = (const int*)d_in[3];
    const void* Wq  = d_in[4];
    const void* bq  = d_in[5];
    const void* Wkv = d_in[6];
    const void* bkv = d_in[7];
    const void* fvw1 = d_in[8];
    const void* fvb1 = d_in[9];
    const void* fvw2 = d_in[10];
    const void* fvb2 = d_in[11];
    const void* fcw1 = d_in[12];
    const void* fcb1 = d_in[13];
    const void* fcw2 = d_in[14];
    const void* fcb2 = d_in[15];
    const void* lavg = d_in[16];
    const void* lavb = d_in[17];
    const void* lfvg = d_in[18];
    const void* lfvb = d_in[19];
    const void* lacg = d_in[20];
    const void* lacb = d_in[21];
    const void* lfcg = d_in[22];
    const void* lfcb = d_in[23];

    const int NV = in_sizes[0] / DD;
    const int NC = in_sizes[1] / DD;
    const int NT = NV + NC;
    const int E  = in_sizes[2] / 2;

    // workspace layout
    char* w = (char*)d_ws;
    int* flagp = (int*)w;                                     // dtype flag (256B slot)
    size_t off = 256;
    float* osum = (float*)(w + off);                          // NT x 256 f32 (attn accum; later ffn2 out)
    off += (size_t)NT * DD * 4;
    unsigned short* qbuf = (unsigned short*)(w + off);        // NT x 256 bf16 (later x1)
    off += (size_t)NT * DD * 2;
    unsigned short* kvbuf = (unsigned short*)(w + off);       // NT x 512 bf16 (later ffn hidden)
    off += (size_t)NT * DD * 4;
    unsigned* mbuf = (unsigned*)(w + off);                    // NT x 8 encoded max
    off += (size_t)NT * NH * 4;
    float* sbuf = (float*)(w + off);                          // NT x 8 denom
    off += (size_t)NT * NH * 4;
    float* qkbuf = (float*)(w + off);                         // E x 2 x 8 logits/exp

    dim3 blk(256);

    detect_dtype<<<dim3(1), dim3(1), 0, stream>>>((const unsigned*)lavg, flagp);

    // shared projections: q = x@Wq+bq ; kv = x@Wkv+bkv  (x = [v; c])
    gemm_k256<1, 0><<<dim3((NV + 63) / 64, DD / 64), blk, 0, stream>>>(v, NV, Wq, DD, bq, qbuf, flagp);
    gemm_k256<1, 0><<<dim3((NC + 63) / 64, DD / 64), blk, 0, stream>>>(c, NC, Wq, DD, bq, qbuf + (size_t)NV * DD, flagp);
    gemm_k256<1, 0><<<dim3((NV + 63) / 64, 512 / 64), blk, 0, stream>>>(v, NV, Wkv, 512, bkv, kvbuf, flagp);
    gemm_k256<1, 0><<<dim3((NC + 63) / 64, 512 / 64), blk, 0, stream>>>(c, NC, Wkv, 512, bkv, kvbuf + (size_t)NV * 512, flagp);

    hipMemsetAsync(osum, 0, (size_t)NT * DD * 4, stream);

    int ntL = E * 16, ntA = E * 64;
    for (int p = 0; p < 2; ++p) {
        const int* adj = p ? adj_neg : adj_pos;
        hipMemsetAsync(mbuf, 0, (size_t)NT * NH * 8, stream);   // mbuf+sbuf contiguous
        edge_logits<<<dim3((ntL + 255) / 256), blk, 0, stream>>>(adj, E, NV, qbuf, kvbuf, qkbuf, mbuf);
        edge_exp   <<<dim3((ntL + 255) / 256), blk, 0, stream>>>(adj, E, NV, qkbuf, mbuf, sbuf);
        edge_agg   <<<dim3((ntA + 255) / 256), blk, 0, stream>>>(adj, E, NV, qkbuf, sbuf, kvbuf, osum);
    }

    // x1 = LN(x + attn) -> overwrite qbuf (internal bf16)
    unsigned short* x1 = qbuf;
    ln_res<1, 0><<<dim3((NT + 3) / 4), blk, 0, stream>>>(v, c, osum, lavg, lavb, lacg, lacb,
                                                         x1, NV, NT, flagp);

    // FFN: h = gelu(x1@W1+b1) -> kvbuf region (stride 256); z = h@W2+b2 -> osum (f32)
    unsigned short* hbuf = kvbuf;
    gemm_k256<0, 1><<<dim3((NV + 63) / 64, DD / 64), blk, 0, stream>>>(x1, NV, fvw1, DD, fvb1, hbuf, flagp);
    gemm_k256<0, 1><<<dim3((NC + 63) / 64, DD / 64), blk, 0, stream>>>(x1 + (size_t)NV * DD, NC, fcw1, DD, fcb1, hbuf + (size_t)NV * DD, flagp);
    gemm_k256<0, 2><<<dim3((NV + 63) / 64, DD / 64), blk, 0, stream>>>(hbuf, NV, fvw2, DD, fvb2, osum, flagp);
    gemm_k256<0, 2><<<dim3((NC + 63) / 64, DD / 64), blk, 0, stream>>>(hbuf + (size_t)NV * DD, NC, fcw2, DD, fcb2, osum + (size_t)NV * DD, flagp);

    // out = LN(x1 + z) -> d_out
    ln_res<0, 1><<<dim3((NT + 3) / 4), blk, 0, stream>>>(x1, x1 + (size_t)NV * DD, osum,
                                                         lfvg, lfvb, lfcg, lfcb,
                                                         d_out, NV, NT, flagp);
}

// Round 3
// 986.454 us; speedup vs baseline: 4.2605x; 4.2605x over previous
//
#include <hip/hip_runtime.h>
#include <math.h>

#define DD 256
#define NH 8

typedef __attribute__((ext_vector_type(8))) short short8;
typedef __attribute__((ext_vector_type(4))) float floatx4;

__device__ __forceinline__ float b2f(unsigned short u) {
    return __uint_as_float(((unsigned)u) << 16);
}
__device__ __forceinline__ unsigned short f2b(float f) {
    unsigned u = __float_as_uint(f);
    return (unsigned short)((u + 0x7fffu + ((u >> 16) & 1u)) >> 16);
}

// ln_att_v_g is all-ones: f32 word0 = 0x3F800000, bf16 word0 = 0x3F803F80
__global__ void detect_dtype(const unsigned* __restrict__ ones_words, int* __restrict__ flag) {
    flag[0] = (ones_words[0] == 0x3F800000u) ? 0 : 1;   // 0 = f32 external, 1 = bf16 external
}

// load 8 consecutive elements as bf16 (f32 path converts on the fly)
__device__ __forceinline__ void load8(const void* base, size_t off, int f32, unsigned short* dst) {
    if (f32) {
        const float4* p = (const float4*)((const float*)base + off);
        float4 x = p[0], y = p[1];
        dst[0] = f2b(x.x); dst[1] = f2b(x.y); dst[2] = f2b(x.z); dst[3] = f2b(x.w);
        dst[4] = f2b(y.x); dst[5] = f2b(y.y); dst[6] = f2b(y.z); dst[7] = f2b(y.w);
    } else {
        *(uint4*)dst = *(const uint4*)((const unsigned short*)base + off);
    }
}

// C = A(MxK=256) @ W(256xN) + bias. A external iff A_EXT (else internal bf16).
// W/bias always external. EPI: 0=bf16 store, 1=gelu->bf16, 2=f32 store
template<int A_EXT, int EPI>
__launch_bounds__(256)
__global__ void gemm_k256(const void* __restrict__ A, int M,
                          const void* __restrict__ W, int ldw,
                          const void* __restrict__ bias,
                          void* __restrict__ outp, const int* __restrict__ flagp)
{
    const int extf = (*flagp == 0);   // 1 if external tensors are f32
    __shared__ __align__(16) short As[64][32];
    __shared__ __align__(16) short Bs[64][32];   // B transposed: Bs[n][k]
    const int t = threadIdx.x;
    const int wave = t >> 6, lane = t & 63;
    const int m0 = blockIdx.x * 64, n0 = blockIdx.y * 64;
    floatx4 acc[4] = {};
    const int arow = t >> 2, acol = (t & 3) * 8;  // A: 64 rows x 32 k
    const int wrow = t >> 3, wcol = (t & 7) * 8;  // W: 32 rows x 64 n
    const int fr = lane & 15, fq = lane >> 4;

    for (int k0 = 0; k0 < DD; k0 += 32) {
        unsigned short a8[8] = {0, 0, 0, 0, 0, 0, 0, 0};
        if (m0 + arow < M)
            load8(A, (size_t)(m0 + arow) * DD + k0 + acol, A_EXT && extf, a8);
        *(uint4*)(&As[arow][acol]) = *(const uint4*)a8;
        unsigned short w8[8];
        load8(W, (size_t)(k0 + wrow) * ldw + n0 + wcol, extf, w8);
        #pragma unroll
        for (int j = 0; j < 8; ++j) Bs[wcol + j][wrow] = (short)w8[j];
        __syncthreads();
        short8 af = *(const short8*)(&As[wave * 16 + fr][fq * 8]);
        #pragma unroll
        for (int j = 0; j < 4; ++j) {
            short8 bf = *(const short8*)(&Bs[j * 16 + fr][fq * 8]);
            acc[j] = __builtin_amdgcn_mfma_f32_16x16x32_bf16(af, bf, acc[j], 0, 0, 0);
        }
        __syncthreads();
    }
    #pragma unroll
    for (int j = 0; j < 4; ++j) {
        int col = n0 + j * 16 + fr;
        float bv = extf ? ((const float*)bias)[col] : b2f(((const unsigned short*)bias)[col]);
        #pragma unroll
        for (int r = 0; r < 4; ++r) {
            int row = m0 + wave * 16 + fq * 4 + r;
            if (row < M) {
                float x = acc[j][r] + bv;
                if (EPI == 1) x = 0.5f * x * (1.0f + erff(x * 0.70710678118654752f));
                if (EPI == 2) {
                    ((float*)outp)[(size_t)row * ldw + col] = x;
                } else {
                    ((unsigned short*)outp)[(size_t)row * ldw + col] = f2b(x);
                }
            }
        }
    }
}

// ---------------- CSR build ----------------
__global__ void csr_count(const int* __restrict__ adj, int E, int NV, int* __restrict__ counts) {
    int e = blockIdx.x * 256 + threadIdx.x;
    if (e >= E) return;
    atomicAdd(&counts[adj[E + e]], 1);          // dir0: seg = variable xe
    atomicAdd(&counts[NV + adj[e]], 1);         // dir1: seg = NV + clause ce
}

__global__ void scan_block(const int* __restrict__ counts, int* __restrict__ offs,
                           int* __restrict__ bsum, int n) {
    __shared__ int sm[256];
    int i = blockIdx.x * 256 + threadIdx.x;
    int x = (i < n) ? counts[i] : 0;
    sm[threadIdx.x] = x;
    __syncthreads();
    #pragma unroll
    for (int d = 1; d < 256; d <<= 1) {
        int t = (threadIdx.x >= d) ? sm[threadIdx.x - d] : 0;
        __syncthreads();
        sm[threadIdx.x] += t;
        __syncthreads();
    }
    if (i < n) offs[i] = sm[threadIdx.x] - x;        // exclusive within block
    if (threadIdx.x == 255) bsum[blockIdx.x] = sm[255];
}

__global__ void scan_bsum(int* __restrict__ bsum, int nb) {
    __shared__ int sm[256];
    __shared__ int carry;
    if (threadIdx.x == 0) carry = 0;
    __syncthreads();
    for (int base = 0; base < nb; base += 256) {
        int i = base + threadIdx.x;
        int x = (i < nb) ? bsum[i] : 0;
        sm[threadIdx.x] = x;
        __syncthreads();
        #pragma unroll
        for (int d = 1; d < 256; d <<= 1) {
            int t = (threadIdx.x >= d) ? sm[threadIdx.x - d] : 0;
            __syncthreads();
            sm[threadIdx.x] += t;
            __syncthreads();
        }
        int excl = sm[threadIdx.x] - x + carry;
        if (i < nb) bsum[i] = excl;
        __syncthreads();
        if (threadIdx.x == 0) carry += sm[255];
        __syncthreads();
    }
}

__global__ void scan_add(int* __restrict__ offs, const int* __restrict__ bsum, int n) {
    int i = blockIdx.x * 256 + threadIdx.x;
    if (i < n) offs[i] += bsum[blockIdx.x];
}

// fill destroys offs: afterwards offs[seg] == end of segment (beg = end - count)
__global__ void csr_fill(const int* __restrict__ adj, int E, int NV,
                         int* __restrict__ offs, int* __restrict__ eids) {
    int e = blockIdx.x * 256 + threadIdx.x;
    if (e >= E) return;
    int p0 = atomicAdd(&offs[adj[E + e]], 1);
    eids[p0] = e * 2;
    int p1 = atomicAdd(&offs[NV + adj[e]], 1);
    eids[p1] = e * 2 + 1;
}

// ---------------- edge logits (no atomics) ----------------
__launch_bounds__(256)
__global__ void edge_logits(const int* __restrict__ adj, int E, int NV,
                            const unsigned short* __restrict__ qbuf,
                            const unsigned short* __restrict__ kvbuf,
                            float* __restrict__ qk)
{
    int t = blockIdx.x * 256 + threadIdx.x;
    if (t >= E * 16) return;
    int e = t >> 4, rem = t & 15;
    int dir = rem >> 3, h = rem & 7;
    int ce = adj[e], xe = adj[E + e];
    int qrow = dir ? (NV + ce) : xe;
    int krow = dir ? xe : (NV + ce);
    const unsigned short* qp = qbuf + (size_t)qrow * DD + h * 32;
    const unsigned short* kp = kvbuf + (size_t)krow * 512 + h * 32;
    float s = 0.f;
    #pragma unroll
    for (int i = 0; i < 4; ++i) {
        uint4 qv = ((const uint4*)qp)[i];
        uint4 kv = ((const uint4*)kp)[i];
        const unsigned short* qa = (const unsigned short*)&qv;
        const unsigned short* ka = (const unsigned short*)&kv;
        #pragma unroll
        for (int j = 0; j < 8; ++j) s += b2f(qa[j]) * b2f(ka[j]);
    }
    // qk index = (e*2+dir)*8 + h  ==  e*16 + dir*8 + h == t
    qk[t] = s * 0.17677669529663689f;   // 1/sqrt(32)
}

// ---------------- per-segment softmax + V aggregation (owner-computes, no atomics) ----
__launch_bounds__(256)
__global__ void seg_attn(const int* __restrict__ offs_end, const int* __restrict__ counts,
                         const int* __restrict__ eids, const int* __restrict__ adj,
                         int E, int NV, const float* __restrict__ qk,
                         const unsigned short* __restrict__ kvbuf,
                         float* __restrict__ osum, int NT, int acc_mode)
{
    int seg = blockIdx.x * 4 + (threadIdx.x >> 6);
    if (seg >= NT) return;
    int lane = threadIdx.x & 63;
    int deg = counts[seg];
    float4* op = (float4*)(osum + (size_t)seg * DD) + lane;
    if (deg == 0) {
        if (!acc_mode) *op = make_float4(0.f, 0.f, 0.f, 0.f);
        return;
    }
    int beg = offs_end[seg] - deg;
    int slot = lane >> 3, h = lane & 7;     // 8 edge-slots x 8 heads
    // pass 1: per-head max over edges
    float m = -1e30f;
    for (int j = slot; j < deg; j += 8)
        m = fmaxf(m, qk[(size_t)eids[beg + j] * 8 + h]);
    m = fmaxf(m, __shfl_xor(m, 8));
    m = fmaxf(m, __shfl_xor(m, 16));
    m = fmaxf(m, __shfl_xor(m, 32));
    // pass 2: per-head exp-sum
    float s = 0.f;
    for (int j = slot; j < deg; j += 8)
        s += __expf(qk[(size_t)eids[beg + j] * 8 + h] - m);
    s += __shfl_xor(s, 8);
    s += __shfl_xor(s, 16);
    s += __shfl_xor(s, 32);
    // transpose (slot,h) -> channel layout: lane covers channels 4*lane..4*lane+3, head = lane>>3
    int h3 = lane >> 3;
    float m3 = __shfl(m, h3);
    float rs3 = 1.f / __shfl(s, h3);
    float a0 = 0.f, a1 = 0.f, a2 = 0.f, a3 = 0.f;
    for (int j = 0; j < deg; ++j) {
        int eid = eids[beg + j];
        int e = eid >> 1, dir = eid & 1;
        int krow = dir ? adj[E + e] : (NV + adj[e]);
        float alpha = __expf(qk[(size_t)eid * 8 + h3] - m3) * rs3;
        ushort4 vv = *(const ushort4*)(kvbuf + (size_t)krow * 512 + DD + lane * 4);
        a0 += alpha * b2f(vv.x);
        a1 += alpha * b2f(vv.y);
        a2 += alpha * b2f(vv.z);
        a3 += alpha * b2f(vv.w);
    }
    float4 o;
    if (acc_mode) {
        float4 old = *op;
        o.x = old.x + a0; o.y = old.y + a1; o.z = old.z + a2; o.w = old.w + a3;
    } else {
        o.x = a0; o.y = a1; o.z = a2; o.w = a3;
    }
    *op = o;
}

// LN(base + add). BASE_EXT: base is external tensor; OUT_EXT: out may be f32 d_out.
template<int BASE_EXT, int OUT_EXT>
__launch_bounds__(256)
__global__ void ln_res(const void* __restrict__ baseA, const void* __restrict__ baseB,
                       const float* __restrict__ add,
                       const void* __restrict__ gA, const void* __restrict__ bA,
                       const void* __restrict__ gB, const void* __restrict__ bB,
                       void* __restrict__ out, int NA, int Ntot, const int* __restrict__ flagp)
{
    int row = blockIdx.x * 4 + (threadIdx.x >> 6);
    if (row >= Ntot) return;
    int lane = threadIdx.x & 63;
    const int extf = (*flagp == 0);
    const void *base, *g, *b;
    size_t roff;
    if (row < NA) { base = baseA; g = gA; b = bA; roff = (size_t)row * DD; }
    else          { base = baseB; g = gB; b = bB; roff = (size_t)(row - NA) * DD; }
    float4 a = ((const float4*)(add + (size_t)row * DD))[lane];
    float y0, y1, y2, y3;
    if (BASE_EXT && extf) {
        float4 t = ((const float4*)((const float*)base + roff))[lane];
        y0 = t.x; y1 = t.y; y2 = t.z; y3 = t.w;
    } else {
        ushort4 t = ((const ushort4*)((const unsigned short*)base + roff))[lane];
        y0 = b2f(t.x); y1 = b2f(t.y); y2 = b2f(t.z); y3 = b2f(t.w);
    }
    y0 += a.x; y1 += a.y; y2 += a.z; y3 += a.w;
    float s = y0 + y1 + y2 + y3;
    #pragma unroll
    for (int off = 32; off; off >>= 1) s += __shfl_xor(s, off);
    float mean = s * (1.0f / DD);
    float d0 = y0 - mean, d1 = y1 - mean, d2 = y2 - mean, d3 = y3 - mean;
    float v = d0 * d0 + d1 * d1 + d2 * d2 + d3 * d3;
    #pragma unroll
    for (int off = 32; off; off >>= 1) v += __shfl_xor(v, off);
    float rstd = rsqrtf(v * (1.0f / DD) + 1e-5f);
    float g0, g1, g2, g3, t0, t1, t2, t3;
    if (extf) {
        float4 gg = ((const float4*)g)[lane]; float4 bt = ((const float4*)b)[lane];
        g0 = gg.x; g1 = gg.y; g2 = gg.z; g3 = gg.w;
        t0 = bt.x; t1 = bt.y; t2 = bt.z; t3 = bt.w;
    } else {
        ushort4 gg = ((const ushort4*)g)[lane]; ushort4 bt = ((const ushort4*)b)[lane];
        g0 = b2f(gg.x); g1 = b2f(gg.y); g2 = b2f(gg.z); g3 = b2f(gg.w);
        t0 = b2f(bt.x); t1 = b2f(bt.y); t2 = b2f(bt.z); t3 = b2f(bt.w);
    }
    float o0 = d0 * rstd * g0 + t0, o1 = d1 * rstd * g1 + t1;
    float o2 = d2 * rstd * g2 + t2, o3 = d3 * rstd * g3 + t3;
    if (OUT_EXT && extf) {
        float4 o; o.x = o0; o.y = o1; o.z = o2; o.w = o3;
        ((float4*)((float*)out + (size_t)row * DD))[lane] = o;
    } else {
        ushort4 o;
        o.x = f2b(o0); o.y = f2b(o1); o.z = f2b(o2); o.w = f2b(o3);
        ((ushort4*)((unsigned short*)out + (size_t)row * DD))[lane] = o;
    }
}

extern "C" void kernel_launch(void* const* d_in, const int* in_sizes, int n_in,
                              void* d_out, int out_size, void* d_ws, size_t ws_size,
                              hipStream_t stream)
{
    const void* v   = d_in[0];
    const void* c   = d_in[1];
    const int* adj_pos = (const int*)d_in[2];
    const int* adj_neg = (const int*)d_in[3];
    const void* Wq  = d_in[4];
    const void* bq  = d_in[5];
    const void* Wkv = d_in[6];
    const void* bkv = d_in[7];
    const void* fvw1 = d_in[8];
    const void* fvb1 = d_in[9];
    const void* fvw2 = d_in[10];
    const void* fvb2 = d_in[11];
    const void* fcw1 = d_in[12];
    const void* fcb1 = d_in[13];
    const void* fcw2 = d_in[14];
    const void* fcb2 = d_in[15];
    const void* lavg = d_in[16];
    const void* lavb = d_in[17];
    const void* lfvg = d_in[18];
    const void* lfvb = d_in[19];
    const void* lacg = d_in[20];
    const void* lacb = d_in[21];
    const void* lfcg = d_in[22];
    const void* lfcb = d_in[23];

    const int NV = in_sizes[0] / DD;
    const int NC = in_sizes[1] / DD;
    const int NT = NV + NC;
    const int E  = in_sizes[2] / 2;

    // workspace layout (16B-aligned blocks first)
    char* w = (char*)d_ws;
    int* flagp = (int*)w;                                     // 256B slot
    size_t off = 256;
    float* osum = (float*)(w + off);                          // NT x 256 f32
    off += (size_t)NT * DD * 4;
    unsigned short* qbuf = (unsigned short*)(w + off);        // NT x 256 bf16 (later x1)
    off += (size_t)NT * DD * 2;
    unsigned short* kvbuf = (unsigned short*)(w + off);       // NT x 512 bf16 (later ffn hidden)
    off += (size_t)NT * DD * 4;
    float* qkbuf = (float*)(w + off);                         // E x 2 x 8 logits (per polarity, reused)
    off += (size_t)E * 16 * 4;
    int* counts = (int*)(w + off);                            // 2 x NT
    off += (size_t)2 * NT * 4;
    int* offs = (int*)(w + off);                              // 2 x NT (becomes "end" after fill)
    off += (size_t)2 * NT * 4;
    int* eids = (int*)(w + off);                              // 2 x 2E
    off += (size_t)2 * 2 * E * 4;
    int* bsum = (int*)(w + off);                              // scan partials

    dim3 blk(256);
    const int nbNT = (NT + 255) / 256;
    const int nbE  = (E + 255) / 256;

    detect_dtype<<<dim3(1), dim3(1), 0, stream>>>((const unsigned*)lavg, flagp);

    // shared projections: q = x@Wq+bq ; kv = x@Wkv+bkv  (x = [v; c])
    gemm_k256<1, 0><<<dim3((NV + 63) / 64, DD / 64), blk, 0, stream>>>(v, NV, Wq, DD, bq, qbuf, flagp);
    gemm_k256<1, 0><<<dim3((NC + 63) / 64, DD / 64), blk, 0, stream>>>(c, NC, Wq, DD, bq, qbuf + (size_t)NV * DD, flagp);
    gemm_k256<1, 0><<<dim3((NV + 63) / 64, 512 / 64), blk, 0, stream>>>(v, NV, Wkv, 512, bkv, kvbuf, flagp);
    gemm_k256<1, 0><<<dim3((NC + 63) / 64, 512 / 64), blk, 0, stream>>>(c, NC, Wkv, 512, bkv, kvbuf + (size_t)NV * 512, flagp);

    // CSR build (both polarities)
    hipMemsetAsync(counts, 0, (size_t)2 * NT * 4, stream);
    for (int p = 0; p < 2; ++p) {
        const int* adj = p ? adj_neg : adj_pos;
        int* cnt = counts + (size_t)p * NT;
        int* ofs = offs + (size_t)p * NT;
        int* eid = eids + (size_t)p * 2 * E;
        csr_count<<<dim3(nbE), blk, 0, stream>>>(adj, E, NV, cnt);
        scan_block<<<dim3(nbNT), blk, 0, stream>>>(cnt, ofs, bsum, NT);
        scan_bsum<<<dim3(1), blk, 0, stream>>>(bsum, nbNT);
        scan_add<<<dim3(nbNT), blk, 0, stream>>>(ofs, bsum, NT);
        csr_fill<<<dim3(nbE), blk, 0, stream>>>(adj, E, NV, ofs, eid);
    }

    // attention per polarity: logits then owner-computes softmax+aggregate
    for (int p = 0; p < 2; ++p) {
        const int* adj = p ? adj_neg : adj_pos;
        edge_logits<<<dim3((E * 16 + 255) / 256), blk, 0, stream>>>(adj, E, NV, qbuf, kvbuf, qkbuf);
        seg_attn<<<dim3((NT + 3) / 4), blk, 0, stream>>>(offs + (size_t)p * NT, counts + (size_t)p * NT,
                                                         eids + (size_t)p * 2 * E, adj, E, NV,
                                                         qkbuf, kvbuf, osum, NT, p);
    }

    // x1 = LN(x + attn) -> overwrite qbuf (internal bf16)
    unsigned short* x1 = qbuf;
    ln_res<1, 0><<<dim3((NT + 3) / 4), blk, 0, stream>>>(v, c, osum, lavg, lavb, lacg, lacb,
                                                         x1, NV, NT, flagp);

    // FFN: h = gelu(x1@W1+b1) -> kvbuf region (stride 256); z = h@W2+b2 -> osum (f32)
    unsigned short* hbuf = kvbuf;
    gemm_k256<0, 1><<<dim3((NV + 63) / 64, DD / 64), blk, 0, stream>>>(x1, NV, fvw1, DD, fvb1, hbuf, flagp);
    gemm_k256<0, 1><<<dim3((NC + 63) / 64, DD / 64), blk, 0, stream>>>(x1 + (size_t)NV * DD, NC, fcw1, DD, fcb1, hbuf + (size_t)NV * DD, flagp);
    gemm_k256<0, 2><<<dim3((NV + 63) / 64, DD / 64), blk, 0, stream>>>(hbuf, NV, fvw2, DD, fvb2, osum, flagp);
    gemm_k256<0, 2><<<dim3((NC + 63) / 64, DD / 64), blk, 0, stream>>>(hbuf + (size_t)NV * DD, NC, fcw2, DD, fcb2, osum + (size_t)NV * DD, flagp);

    // out = LN(x1 + z) -> d_out
    ln_res<0, 1><<<dim3((NT + 3) / 4), blk, 0, stream>>>(x1, x1 + (size_t)NV * DD, osum,
                                                         lfvg, lfvb, lfcg, lfcb,
                                                         d_out, NV, NT, flagp);
}

// Round 4
// 783.804 us; speedup vs baseline: 5.3621x; 1.2585x over previous
//
#include <hip/hip_runtime.h>
#include <math.h>

#define DD 256
#define NH 8

typedef __attribute__((ext_vector_type(8))) short short8;
typedef __attribute__((ext_vector_type(4))) float floatx4;

__device__ __forceinline__ float b2f(unsigned short u) {
    return __uint_as_float(((unsigned)u) << 16);
}
__device__ __forceinline__ unsigned short f2b(float f) {
    unsigned u = __float_as_uint(f);
    return (unsigned short)((u + 0x7fffu + ((u >> 16) & 1u)) >> 16);
}

// ln_att_v_g is all-ones: f32 word0 = 0x3F800000, bf16 word0 = 0x3F803F80
__global__ void detect_dtype(const unsigned* __restrict__ ones_words, int* __restrict__ flag) {
    flag[0] = (ones_words[0] == 0x3F800000u) ? 0 : 1;   // 0 = f32 external, 1 = bf16 external
}

// load 8 consecutive elements as bf16 (f32 path converts on the fly)
__device__ __forceinline__ void load8(const void* base, size_t off, int f32, unsigned short* dst) {
    if (f32) {
        const float4* p = (const float4*)((const float*)base + off);
        float4 x = p[0], y = p[1];
        dst[0] = f2b(x.x); dst[1] = f2b(x.y); dst[2] = f2b(x.z); dst[3] = f2b(x.w);
        dst[4] = f2b(y.x); dst[5] = f2b(y.y); dst[6] = f2b(y.z); dst[7] = f2b(y.w);
    } else {
        *(uint4*)dst = *(const uint4*)((const unsigned short*)base + off);
    }
}

// ---------------- W^T build: wt[n][k] = W[k][n], bf16, K=256 ----------------
// wt row offsets: Wq:0, Wkv:256, fvw1:768, fcw1:1024, fvw2:1280, fcw2:1536
__global__ void wt_build(const void* __restrict__ Wq, const void* __restrict__ Wkv,
                         const void* __restrict__ f1v, const void* __restrict__ f1c,
                         const void* __restrict__ f2v, const void* __restrict__ f2c,
                         short* __restrict__ wt, const int* __restrict__ flagp)
{
    const int extf = (*flagp == 0);
    const void* src; int N; size_t dst0;
    switch (blockIdx.z) {
        case 0:  src = Wq;  N = 256; dst0 = 0;          break;
        case 1:  src = Wkv; N = 512; dst0 = 256 * 256;  break;
        case 2:  src = f1v; N = 256; dst0 = 768 * 256;  break;
        case 3:  src = f1c; N = 256; dst0 = 1024 * 256; break;
        case 4:  src = f2v; N = 256; dst0 = 1280 * 256; break;
        default: src = f2c; N = 256; dst0 = 1536 * 256; break;
    }
    int n0 = blockIdx.x * 32, k0 = blockIdx.y * 32;
    if (n0 >= N) return;
    __shared__ short tile[32][33];
    int tx = threadIdx.x & 31, ty = threadIdx.x >> 5;   // 8 rows per pass
    #pragma unroll
    for (int i = 0; i < 32; i += 8) {
        int k = k0 + ty + i, n = n0 + tx;
        float val = extf ? ((const float*)src)[(size_t)k * N + n]
                         : b2f(((const unsigned short*)src)[(size_t)k * N + n]);
        tile[ty + i][tx] = (short)f2b(val);
    }
    __syncthreads();
    #pragma unroll
    for (int i = 0; i < 32; i += 8)
        wt[dst0 + (size_t)(n0 + ty + i) * 256 + k0 + tx] = tile[tx][ty + i];
}

// ---------------- fused q+kv projection GEMM, A staged once ----------------
// out q: NT x 256 bf16; kv: NT x 512 bf16. 12 n-chunks (4 q + 8 kv).
__launch_bounds__(256)
__global__ void proj_gemm(const void* __restrict__ va, const void* __restrict__ ca,
                          int NVr, int NCr, int bv,
                          const short* __restrict__ wt,
                          const void* __restrict__ bq, const void* __restrict__ bkv,
                          unsigned short* __restrict__ qbuf, unsigned short* __restrict__ kvbuf,
                          const int* __restrict__ flagp)
{
    const int extf = (*flagp == 0);
    __shared__ __align__(16) short As[64][264];   // +8 pad: row stride 132 dw (mod 32 = 4)
    __shared__ __align__(16) short Bs[64][32];
    const int t = threadIdx.x;
    const int wave = t >> 6, lane = t & 63;
    const int bx = blockIdx.x;
    int grow0, nrows; const void* asrc; size_t abase;
    if (bx < bv) { grow0 = bx * 64; asrc = va; abase = (size_t)grow0 * DD; nrows = NVr - grow0; }
    else { int mc0 = (bx - bv) * 64; grow0 = NVr + mc0; asrc = ca; abase = (size_t)mc0 * DD; nrows = NCr - mc0; }
    if (nrows > 64) nrows = 64;
    {   // stage A-tile 64x256 (full K) once
        const int r = t >> 2, cb = (t & 3) * 8;
        #pragma unroll
        for (int cc = 0; cc < 8; ++cc) {
            int col = cb + cc * 32;
            unsigned short a8[8] = {0, 0, 0, 0, 0, 0, 0, 0};
            if (r < nrows) load8(asrc, abase + (size_t)r * DD + col, extf, a8);
            *(uint4*)(&As[r][col]) = *(const uint4*)a8;
        }
    }
    __syncthreads();
    const int fr = lane & 15, fq = lane >> 4;
    const int brow = t >> 2, bcol = (t & 3) * 8;
    for (int nc = 0; nc < 12; ++nc) {
        const short* wtc = wt + (size_t)nc * 64 * 256;
        floatx4 acc[4] = {};
        for (int k0 = 0; k0 < 256; k0 += 32) {
            *(uint4*)(&Bs[brow][bcol]) = *(const uint4*)(wtc + (size_t)brow * 256 + k0 + bcol);
            __syncthreads();
            short8 af = *(const short8*)(&As[wave * 16 + fr][k0 + fq * 8]);
            #pragma unroll
            for (int j = 0; j < 4; ++j) {
                short8 bf = *(const short8*)(&Bs[j * 16 + fr][fq * 8]);
                acc[j] = __builtin_amdgcn_mfma_f32_16x16x32_bf16(af, bf, acc[j], 0, 0, 0);
            }
            __syncthreads();
        }
        unsigned short* outp; int ldo, colbase; const void* bias;
        if (nc < 4) { outp = qbuf;  ldo = 256; colbase = nc * 64;       bias = bq;  }
        else        { outp = kvbuf; ldo = 512; colbase = (nc - 4) * 64; bias = bkv; }
        #pragma unroll
        for (int j = 0; j < 4; ++j) {
            int col = colbase + j * 16 + fr;
            float bvv = extf ? ((const float*)bias)[col] : b2f(((const unsigned short*)bias)[col]);
            #pragma unroll
            for (int r = 0; r < 4; ++r) {
                int rr = wave * 16 + fq * 4 + r;
                if (rr < nrows)
                    outp[(size_t)(grow0 + rr) * ldo + col] = f2b(acc[j][r] + bvv);
            }
        }
    }
}

// ---------------- FFN GEMM (A internal bf16), per-part W. EPI 1=gelu->bf16, 2=f32 ----
template<int EPI>
__launch_bounds__(256)
__global__ void ffn_gemm(const unsigned short* __restrict__ A,
                         int NVr, int NCr, int bv,
                         const short* __restrict__ wtV, const short* __restrict__ wtC,
                         const void* __restrict__ biasV, const void* __restrict__ biasC,
                         void* __restrict__ outp, const int* __restrict__ flagp)
{
    const int extf = (*flagp == 0);
    __shared__ __align__(16) short As[64][264];
    __shared__ __align__(16) short Bs[64][32];
    const int t = threadIdx.x;
    const int wave = t >> 6, lane = t & 63;
    const int bx = blockIdx.x;
    int grow0, nrows; const short* wtp; const void* bias;
    if (bx < bv) { grow0 = bx * 64; nrows = NVr - grow0; wtp = wtV; bias = biasV; }
    else { grow0 = NVr + (bx - bv) * 64; nrows = NVr + NCr - grow0; wtp = wtC; bias = biasC; }
    if (nrows > 64) nrows = 64;
    {
        const int r = t >> 2, cb = (t & 3) * 8;
        #pragma unroll
        for (int cc = 0; cc < 8; ++cc) {
            int col = cb + cc * 32;
            uint4 a8 = make_uint4(0u, 0u, 0u, 0u);
            if (r < nrows) a8 = *(const uint4*)(A + (size_t)(grow0 + r) * DD + col);
            *(uint4*)(&As[r][col]) = a8;
        }
    }
    __syncthreads();
    const int fr = lane & 15, fq = lane >> 4;
    const int brow = t >> 2, bcol = (t & 3) * 8;
    for (int nc = 0; nc < 4; ++nc) {
        const short* wtc = wtp + (size_t)nc * 64 * 256;
        floatx4 acc[4] = {};
        for (int k0 = 0; k0 < 256; k0 += 32) {
            *(uint4*)(&Bs[brow][bcol]) = *(const uint4*)(wtc + (size_t)brow * 256 + k0 + bcol);
            __syncthreads();
            short8 af = *(const short8*)(&As[wave * 16 + fr][k0 + fq * 8]);
            #pragma unroll
            for (int j = 0; j < 4; ++j) {
                short8 bf = *(const short8*)(&Bs[j * 16 + fr][fq * 8]);
                acc[j] = __builtin_amdgcn_mfma_f32_16x16x32_bf16(af, bf, acc[j], 0, 0, 0);
            }
            __syncthreads();
        }
        #pragma unroll
        for (int j = 0; j < 4; ++j) {
            int col = nc * 64 + j * 16 + fr;
            float bvv = extf ? ((const float*)bias)[col] : b2f(((const unsigned short*)bias)[col]);
            #pragma unroll
            for (int r = 0; r < 4; ++r) {
                int rr = wave * 16 + fq * 4 + r;
                if (rr < nrows) {
                    float x = acc[j][r] + bvv;
                    if (EPI == 1) {
                        x = 0.5f * x * (1.0f + erff(x * 0.70710678118654752f));
                        ((unsigned short*)outp)[(size_t)(grow0 + rr) * DD + col] = f2b(x);
                    } else {
                        ((float*)outp)[(size_t)(grow0 + rr) * DD + col] = x;
                    }
                }
            }
        }
    }
}

// ---------------- CSR build (both polarities; segment space 2*NT) ----------------
__global__ void csr_count(const int* __restrict__ ap, const int* __restrict__ an,
                          int E, int NV, int NT, int* __restrict__ counts) {
    int e = blockIdx.x * 256 + threadIdx.x;
    if (e >= E) return;
    atomicAdd(&counts[ap[E + e]], 1);
    atomicAdd(&counts[NV + ap[e]], 1);
    atomicAdd(&counts[NT + an[E + e]], 1);
    atomicAdd(&counts[NT + NV + an[e]], 1);
}

__global__ void scan_block(const int* __restrict__ counts, int* __restrict__ offs,
                           int* __restrict__ bsum, int n) {
    __shared__ int sm[256];
    int i = blockIdx.x * 256 + threadIdx.x;
    int x = (i < n) ? counts[i] : 0;
    sm[threadIdx.x] = x;
    __syncthreads();
    #pragma unroll
    for (int d = 1; d < 256; d <<= 1) {
        int t = (threadIdx.x >= d) ? sm[threadIdx.x - d] : 0;
        __syncthreads();
        sm[threadIdx.x] += t;
        __syncthreads();
    }
    if (i < n) offs[i] = sm[threadIdx.x] - x;
    if (threadIdx.x == 255) bsum[blockIdx.x] = sm[255];
}

__global__ void scan_bsum(int* __restrict__ bsum, int nb) {
    __shared__ int sm[256];
    __shared__ int carry;
    if (threadIdx.x == 0) carry = 0;
    __syncthreads();
    for (int base = 0; base < nb; base += 256) {
        int i = base + threadIdx.x;
        int x = (i < nb) ? bsum[i] : 0;
        sm[threadIdx.x] = x;
        __syncthreads();
        #pragma unroll
        for (int d = 1; d < 256; d <<= 1) {
            int t = (threadIdx.x >= d) ? sm[threadIdx.x - d] : 0;
            __syncthreads();
            sm[threadIdx.x] += t;
            __syncthreads();
        }
        int excl = sm[threadIdx.x] - x + carry;
        if (i < nb) bsum[i] = excl;
        __syncthreads();
        if (threadIdx.x == 0) carry += sm[255];
        __syncthreads();
    }
}

__global__ void scan_add(int* __restrict__ offs, const int* __restrict__ bsum, int n) {
    int i = blockIdx.x * 256 + threadIdx.x;
    if (i < n) offs[i] += bsum[blockIdx.x];
}

// fill destroys offs: afterwards offs[seg] == end of segment (beg = end - count)
__global__ void csr_fill(const int* __restrict__ ap, const int* __restrict__ an,
                         int E, int NV, int NT, int* __restrict__ offs, int* __restrict__ eids) {
    int e = blockIdx.x * 256 + threadIdx.x;
    if (e >= E) return;
    int p;
    p = atomicAdd(&offs[ap[E + e]], 1);            eids[p] = e * 2;
    p = atomicAdd(&offs[NV + ap[e]], 1);           eids[p] = e * 2 + 1;
    p = atomicAdd(&offs[NT + an[E + e]], 1);       eids[p] = e * 2;
    p = atomicAdd(&offs[NT + NV + an[e]], 1);      eids[p] = e * 2 + 1;
}

// ---------------- edge logits ----------------
__launch_bounds__(256)
__global__ void edge_logits(const int* __restrict__ adj, int E, int NV,
                            const unsigned short* __restrict__ qbuf,
                            const unsigned short* __restrict__ kvbuf,
                            float* __restrict__ qk)
{
    int t = blockIdx.x * 256 + threadIdx.x;
    if (t >= E * 16) return;
    int e = t >> 4, rem = t & 15;
    int dir = rem >> 3, h = rem & 7;
    int ce = adj[e], xe = adj[E + e];
    int qrow = dir ? (NV + ce) : xe;
    int krow = dir ? xe : (NV + ce);
    const unsigned short* qp = qbuf + (size_t)qrow * DD + h * 32;
    const unsigned short* kp = kvbuf + (size_t)krow * 512 + h * 32;
    float s = 0.f;
    #pragma unroll
    for (int i = 0; i < 4; ++i) {
        uint4 qv = ((const uint4*)qp)[i];
        uint4 kv = ((const uint4*)kp)[i];
        const unsigned short* qa = (const unsigned short*)&qv;
        const unsigned short* ka = (const unsigned short*)&kv;
        #pragma unroll
        for (int j = 0; j < 8; ++j) s += b2f(qa[j]) * b2f(ka[j]);
    }
    qk[t] = s * 0.17677669529663689f;   // 1/sqrt(32)
}

// ---------------- per-segment softmax + V aggregation (owner-computes) ----------------
__launch_bounds__(256)
__global__ void seg_attn(const int* __restrict__ offs_end, const int* __restrict__ counts,
                         const int* __restrict__ eids, const int* __restrict__ adj,
                         int E, int NV, const float* __restrict__ qk,
                         const unsigned short* __restrict__ kvbuf,
                         float* __restrict__ osum, int NT, int acc_mode)
{
    int seg = blockIdx.x * 4 + (threadIdx.x >> 6);
    if (seg >= NT) return;
    int lane = threadIdx.x & 63;
    int deg = counts[seg];
    float4* op = (float4*)(osum + (size_t)seg * DD) + lane;
    if (deg == 0) {
        if (!acc_mode) *op = make_float4(0.f, 0.f, 0.f, 0.f);
        return;
    }
    int beg = offs_end[seg] - deg;
    int slot = lane >> 3, h = lane & 7;
    float m = -1e30f;
    for (int j = slot; j < deg; j += 8)
        m = fmaxf(m, qk[(size_t)eids[beg + j] * 8 + h]);
    m = fmaxf(m, __shfl_xor(m, 8));
    m = fmaxf(m, __shfl_xor(m, 16));
    m = fmaxf(m, __shfl_xor(m, 32));
    float s = 0.f;
    for (int j = slot; j < deg; j += 8)
        s += __expf(qk[(size_t)eids[beg + j] * 8 + h] - m);
    s += __shfl_xor(s, 8);
    s += __shfl_xor(s, 16);
    s += __shfl_xor(s, 32);
    int h3 = lane >> 3;
    float m3 = __shfl(m, h3);
    float rs3 = 1.f / __shfl(s, h3);
    float a0 = 0.f, a1 = 0.f, a2 = 0.f, a3 = 0.f;
    for (int j = 0; j < deg; ++j) {
        int eid = eids[beg + j];
        int e = eid >> 1, dir = eid & 1;
        int krow = dir ? adj[E + e] : (NV + adj[e]);
        float alpha = __expf(qk[(size_t)eid * 8 + h3] - m3) * rs3;
        ushort4 vv = *(const ushort4*)(kvbuf + (size_t)krow * 512 + DD + lane * 4);
        a0 += alpha * b2f(vv.x);
        a1 += alpha * b2f(vv.y);
        a2 += alpha * b2f(vv.z);
        a3 += alpha * b2f(vv.w);
    }
    float4 o;
    if (acc_mode) {
        float4 old = *op;
        o.x = old.x + a0; o.y = old.y + a1; o.z = old.z + a2; o.w = old.w + a3;
    } else {
        o.x = a0; o.y = a1; o.z = a2; o.w = a3;
    }
    *op = o;
}

// ---------------- LN(base + add) ----------------
template<int BASE_EXT, int OUT_EXT>
__launch_bounds__(256)
__global__ void ln_res(const void* __restrict__ baseA, const void* __restrict__ baseB,
                       const float* __restrict__ add,
                       const void* __restrict__ gA, const void* __restrict__ bA,
                       const void* __restrict__ gB, const void* __restrict__ bB,
                       void* __restrict__ out, int NA, int Ntot, const int* __restrict__ flagp)
{
    int row = blockIdx.x * 4 + (threadIdx.x >> 6);
    if (row >= Ntot) return;
    int lane = threadIdx.x & 63;
    const int extf = (*flagp == 0);
    const void *base, *g, *b;
    size_t roff;
    if (row < NA) { base = baseA; g = gA; b = bA; roff = (size_t)row * DD; }
    else          { base = baseB; g = gB; b = bB; roff = (size_t)(row - NA) * DD; }
    float4 a = ((const float4*)(add + (size_t)row * DD))[lane];
    float y0, y1, y2, y3;
    if (BASE_EXT && extf) {
        float4 t = ((const float4*)((const float*)base + roff))[lane];
        y0 = t.x; y1 = t.y; y2 = t.z; y3 = t.w;
    } else {
        ushort4 t = ((const ushort4*)((const unsigned short*)base + roff))[lane];
        y0 = b2f(t.x); y1 = b2f(t.y); y2 = b2f(t.z); y3 = b2f(t.w);
    }
    y0 += a.x; y1 += a.y; y2 += a.z; y3 += a.w;
    float s = y0 + y1 + y2 + y3;
    #pragma unroll
    for (int off = 32; off; off >>= 1) s += __shfl_xor(s, off);
    float mean = s * (1.0f / DD);
    float d0 = y0 - mean, d1 = y1 - mean, d2 = y2 - mean, d3 = y3 - mean;
    float v = d0 * d0 + d1 * d1 + d2 * d2 + d3 * d3;
    #pragma unroll
    for (int off = 32; off; off >>= 1) v += __shfl_xor(v, off);
    float rstd = rsqrtf(v * (1.0f / DD) + 1e-5f);
    float g0, g1, g2, g3, t0, t1, t2, t3;
    if (extf) {
        float4 gg = ((const float4*)g)[lane]; float4 bt = ((const float4*)b)[lane];
        g0 = gg.x; g1 = gg.y; g2 = gg.z; g3 = gg.w;
        t0 = bt.x; t1 = bt.y; t2 = bt.z; t3 = bt.w;
    } else {
        ushort4 gg = ((const ushort4*)g)[lane]; ushort4 bt = ((const ushort4*)b)[lane];
        g0 = b2f(gg.x); g1 = b2f(gg.y); g2 = b2f(gg.z); g3 = b2f(gg.w);
        t0 = b2f(bt.x); t1 = b2f(bt.y); t2 = b2f(bt.z); t3 = b2f(bt.w);
    }
    float o0 = d0 * rstd * g0 + t0, o1 = d1 * rstd * g1 + t1;
    float o2 = d2 * rstd * g2 + t2, o3 = d3 * rstd * g3 + t3;
    if (OUT_EXT && extf) {
        float4 o; o.x = o0; o.y = o1; o.z = o2; o.w = o3;
        ((float4*)((float*)out + (size_t)row * DD))[lane] = o;
    } else {
        ushort4 o;
        o.x = f2b(o0); o.y = f2b(o1); o.z = f2b(o2); o.w = f2b(o3);
        ((ushort4*)((unsigned short*)out + (size_t)row * DD))[lane] = o;
    }
}

extern "C" void kernel_launch(void* const* d_in, const int* in_sizes, int n_in,
                              void* d_out, int out_size, void* d_ws, size_t ws_size,
                              hipStream_t stream)
{
    const void* v   = d_in[0];
    const void* c   = d_in[1];
    const int* adj_pos = (const int*)d_in[2];
    const int* adj_neg = (const int*)d_in[3];
    const void* Wq  = d_in[4];
    const void* bq  = d_in[5];
    const void* Wkv = d_in[6];
    const void* bkv = d_in[7];
    const void* fvw1 = d_in[8];
    const void* fvb1 = d_in[9];
    const void* fvw2 = d_in[10];
    const void* fvb2 = d_in[11];
    const void* fcw1 = d_in[12];
    const void* fcb1 = d_in[13];
    const void* fcw2 = d_in[14];
    const void* fcb2 = d_in[15];
    const void* lavg = d_in[16];
    const void* lavb = d_in[17];
    const void* lfvg = d_in[18];
    const void* lfvb = d_in[19];
    const void* lacg = d_in[20];
    const void* lacb = d_in[21];
    const void* lfcg = d_in[22];
    const void* lfcb = d_in[23];

    const int NV = in_sizes[0] / DD;
    const int NC = in_sizes[1] / DD;
    const int NT = NV + NC;
    const int E  = in_sizes[2] / 2;

    // workspace layout
    char* w = (char*)d_ws;
    int* flagp = (int*)w;                                     // 256B slot
    size_t off = 256;
    float* osum = (float*)(w + off);                          // NT x 256 f32
    off += (size_t)NT * DD * 4;
    unsigned short* qbuf = (unsigned short*)(w + off);        // NT x 256 bf16 (later x1)
    off += (size_t)NT * DD * 2;
    unsigned short* kvbuf = (unsigned short*)(w + off);       // NT x 512 bf16 (later ffn hidden)
    off += (size_t)NT * DD * 4;
    float* qkbuf = (float*)(w + off);                         // E x 2 x 8 logits (per polarity)
    off += (size_t)E * 16 * 4;
    int* counts = (int*)(w + off);                            // 2 x NT
    off += (size_t)2 * NT * 4;
    int* offs = (int*)(w + off);                              // 2 x NT (becomes "end" after fill)
    off += (size_t)2 * NT * 4;
    int* eids = (int*)(w + off);                              // 4E entries (global positions)
    off += (size_t)4 * E * 4;
    int* bsum = (int*)(w + off);                              // scan partials
    off += 4096;
    short* wt = (short*)(w + off);                            // 1792 x 256 bf16 W^T

    dim3 blk(256);
    const int bv = (NV + 63) / 64, bc = (NC + 63) / 64;
    const int nbE = (E + 255) / 256;
    const int n2 = 2 * NT, nb2 = (n2 + 255) / 256;

    detect_dtype<<<dim3(1), dim3(1), 0, stream>>>((const unsigned*)lavg, flagp);
    wt_build<<<dim3(16, 8, 6), blk, 0, stream>>>(Wq, Wkv, fvw1, fcw1, fvw2, fcw2, wt, flagp);

    // fused q+kv projection (A fetched once)
    proj_gemm<<<dim3(bv + bc), blk, 0, stream>>>(v, c, NV, NC, bv, wt, bq, bkv, qbuf, kvbuf, flagp);

    // CSR build, both polarities in one segment space [2*NT]
    hipMemsetAsync(counts, 0, (size_t)n2 * 4, stream);
    csr_count<<<dim3(nbE), blk, 0, stream>>>(adj_pos, adj_neg, E, NV, NT, counts);
    scan_block<<<dim3(nb2), blk, 0, stream>>>(counts, offs, bsum, n2);
    scan_bsum<<<dim3(1), blk, 0, stream>>>(bsum, nb2);
    scan_add<<<dim3(nb2), blk, 0, stream>>>(offs, bsum, n2);
    csr_fill<<<dim3(nbE), blk, 0, stream>>>(adj_pos, adj_neg, E, NV, NT, offs, eids);

    // attention per polarity
    for (int p = 0; p < 2; ++p) {
        const int* adj = p ? adj_neg : adj_pos;
        edge_logits<<<dim3((E * 16 + 255) / 256), blk, 0, stream>>>(adj, E, NV, qbuf, kvbuf, qkbuf);
        seg_attn<<<dim3((NT + 3) / 4), blk, 0, stream>>>(offs + (size_t)p * NT, counts + (size_t)p * NT,
                                                         eids, adj, E, NV, qkbuf, kvbuf, osum, NT, p);
    }

    // x1 = LN(x + attn) -> overwrite qbuf (internal bf16)
    unsigned short* x1 = qbuf;
    ln_res<1, 0><<<dim3((NT + 3) / 4), blk, 0, stream>>>(v, c, osum, lavg, lavb, lacg, lacb,
                                                         x1, NV, NT, flagp);

    // FFN: h = gelu(x1@W1+b1) -> hbuf (kvbuf region); z = h@W2+b2 -> osum (f32)
    unsigned short* hbuf = kvbuf;
    ffn_gemm<1><<<dim3(bv + bc), blk, 0, stream>>>(x1, NV, NC, bv,
                                                   wt + (size_t)768 * 256, wt + (size_t)1024 * 256,
                                                   fvb1, fcb1, hbuf, flagp);
    ffn_gemm<2><<<dim3(bv + bc), blk, 0, stream>>>(hbuf, NV, NC, bv,
                                                   wt + (size_t)1280 * 256, wt + (size_t)1536 * 256,
                                                   fvb2, fcb2, osum, flagp);

    // out = LN(x1 + z) -> d_out
    ln_res<0, 1><<<dim3((NT + 3) / 4), blk, 0, stream>>>(x1, x1 + (size_t)NV * DD, osum,
                                                         lfvg, lfvb, lfcg, lfcb,
                                                         d_out, NV, NT, flagp);
}